// Round 1
// baseline (895.216 us; speedup 1.0000x reference)
//
#include <hip/hip_runtime.h>
#include <hip/hip_fp16.h>

#define N_NODES 50000
#define N_EDGES 800000
#define DIM 128

typedef _Float16 f16;
typedef _Float16 f16x2 __attribute__((ext_vector_type(2)));
typedef _Float16 f16x8 __attribute__((ext_vector_type(8)));
typedef float    f32x16 __attribute__((ext_vector_type(16)));

// ---------------- MFMA GEMM building blocks ----------------
// LDS tile: 128 rows x 128 f16, row = 256B = 16 slots of 16B, slot swizzle s^(row&15)
__device__ __forceinline__ void stage_tile(const float* __restrict__ src, long row0, long nrows,
                                           f16* __restrict__ lds) {
#pragma unroll
  for (int ii = 0; ii < 8; ++ii) {
    int i = threadIdx.x + ii * 256;     // blockDim == 256
    int r = i >> 4, s = i & 15;
    long gr = row0 + r;
    float4 v0 = make_float4(0.f, 0.f, 0.f, 0.f), v1 = v0;
    if (gr < nrows) {
      const float4* p = (const float4*)(src + gr * DIM + s * 8);
      v0 = p[0]; v1 = p[1];
    }
    f16x8 h;
    h[0] = (f16)v0.x; h[1] = (f16)v0.y; h[2] = (f16)v0.z; h[3] = (f16)v0.w;
    h[4] = (f16)v1.x; h[5] = (f16)v1.y; h[6] = (f16)v1.z; h[7] = (f16)v1.w;
    *(f16x8*)(lds + r * DIM + (s ^ (r & 15)) * 8) = h;
  }
}

__device__ __forceinline__ f16x8 frag(const f16* __restrict__ lds, int row, int ks, int g) {
  int slot = (2 * ks + g) ^ (row & 15);
  return *(const f16x8*)(lds + row * DIM + slot * 8);
}

__device__ __forceinline__ void zero_acc(f32x16 acc[2][2]) {
#pragma unroll
  for (int i = 0; i < 2; ++i)
#pragma unroll
    for (int j = 0; j < 2; ++j)
#pragma unroll
      for (int k = 0; k < 16; ++k) acc[i][j][k] = 0.0f;
}

__device__ __forceinline__ void mfma_tile(const f16* __restrict__ xs, const f16* __restrict__ wsh,
                                          f32x16 acc[2][2], int wr, int wc, int l31, int g) {
#pragma unroll
  for (int ks = 0; ks < 8; ++ks) {
    f16x8 a0 = frag(xs, wr * 64 + l31,      ks, g);
    f16x8 a1 = frag(xs, wr * 64 + 32 + l31, ks, g);
    f16x8 b0 = frag(wsh, wc * 64 + l31,      ks, g);
    f16x8 b1 = frag(wsh, wc * 64 + 32 + l31, ks, g);
    acc[0][0] = __builtin_amdgcn_mfma_f32_32x32x16_f16(a0, b0, acc[0][0], 0, 0, 0);
    acc[0][1] = __builtin_amdgcn_mfma_f32_32x32x16_f16(a0, b1, acc[0][1], 0, 0, 0);
    acc[1][0] = __builtin_amdgcn_mfma_f32_32x32x16_f16(a1, b0, acc[1][0], 0, 0, 0);
    acc[1][1] = __builtin_amdgcn_mfma_f32_32x32x16_f16(a1, b1, acc[1][1], 0, 0, 0);
  }
}

template <int HALF_OUT, int SILU>
__device__ __forceinline__ void store_tile(f32x16 acc[2][2], long m0, long M,
                                           const float* __restrict__ bias, void* __restrict__ out,
                                           int wr, int wc, int l31, int g) {
#pragma unroll
  for (int ci = 0; ci < 2; ++ci) {
    int col = wc * 64 + ci * 32 + l31;
    float bv = bias[col];
#pragma unroll
    for (int ri = 0; ri < 2; ++ri) {
#pragma unroll
      for (int r = 0; r < 16; ++r) {
        long gm = m0 + wr * 64 + ri * 32 + ((r & 3) + 8 * (r >> 2) + 4 * g);
        if (gm < M) {
          float v = acc[ri][ci][r] + bv;
          if (SILU) v = v / (1.0f + __expf(-v));
          if (HALF_OUT) ((f16*)out)[gm * DIM + col] = (f16)v;
          else          ((float*)out)[gm * DIM + col] = v;
        }
      }
    }
  }
}

template <int HALF_OUT, int SILU>
__global__ __launch_bounds__(256) void gemm128(const float* __restrict__ X, long M,
                                               const float* __restrict__ W,
                                               const float* __restrict__ B,
                                               void* __restrict__ OUT) {
  __shared__ f16 xs[DIM * DIM];
  __shared__ f16 wsh[DIM * DIM];
  long m0 = (long)blockIdx.x * DIM;
  stage_tile(X, m0, M, xs);
  stage_tile(W, 0, DIM, wsh);
  __syncthreads();
  int lane = threadIdx.x & 63, w = threadIdx.x >> 6;
  int wr = w >> 1, wc = w & 1, l31 = lane & 31, g = lane >> 5;
  f32x16 acc[2][2];
  zero_acc(acc);
  mfma_tile(xs, wsh, acc, wr, wc, l31, g);
  store_tile<HALF_OUT, SILU>(acc, m0, M, B, OUT, wr, wc, l31, g);
}

// Fused node-side GEMMs: Q,K,V (f16 out) + skip (f32 out), X staged once.
__global__ __launch_bounds__(256) void node_qkvs(const float* __restrict__ X,
    const float* __restrict__ Wq, const float* __restrict__ bq,
    const float* __restrict__ Wk, const float* __restrict__ bk,
    const float* __restrict__ Wv, const float* __restrict__ bv,
    const float* __restrict__ Wsk, const float* __restrict__ bsk,
    f16* __restrict__ Q, f16* __restrict__ K, f16* __restrict__ V, float* __restrict__ S) {
  __shared__ f16 xs[DIM * DIM];
  __shared__ f16 wsh[DIM * DIM];
  long m0 = (long)blockIdx.x * DIM;
  stage_tile(X, m0, N_NODES, xs);
  int lane = threadIdx.x & 63, w = threadIdx.x >> 6;
  int wr = w >> 1, wc = w & 1, l31 = lane & 31, g = lane >> 5;
#pragma unroll 1
  for (int mm = 0; mm < 4; ++mm) {
    const float* Wp = (mm == 0) ? Wq : (mm == 1) ? Wk : (mm == 2) ? Wv : Wsk;
    const float* Bp = (mm == 0) ? bq : (mm == 1) ? bk : (mm == 2) ? bv : bsk;
    __syncthreads();
    stage_tile(Wp, 0, DIM, wsh);
    __syncthreads();
    f32x16 acc[2][2];
    zero_acc(acc);
    mfma_tile(xs, wsh, acc, wr, wc, l31, g);
    if (mm == 0)      store_tile<1, 0>(acc, m0, N_NODES, Bp, Q, wr, wc, l31, g);
    else if (mm == 1) store_tile<1, 0>(acc, m0, N_NODES, Bp, K, wr, wc, l31, g);
    else if (mm == 2) store_tile<1, 0>(acc, m0, N_NODES, Bp, V, wr, wc, l31, g);
    else              store_tile<0, 0>(acc, m0, N_NODES, Bp, S, wr, wc, l31, g);
  }
}

// ---------------- CSR build ----------------
__global__ void hist_k(const int* __restrict__ ei, int* __restrict__ counts) {
  for (long e = blockIdx.x * (long)blockDim.x + threadIdx.x; e < N_EDGES;
       e += (long)gridDim.x * blockDim.x)
    atomicAdd(&counts[ei[N_EDGES + e]], 1);
}

__global__ __launch_bounds__(1024) void scan_k(const int* __restrict__ counts,
                                               int* __restrict__ offs, int* __restrict__ cursor) {
  __shared__ int sd[1024];
  int tid = threadIdx.x;
  const int CH = (N_NODES + 1023) / 1024;  // 49
  int i0 = tid * CH;
  int s = 0;
  for (int i = 0; i < CH; ++i) { int idx = i0 + i; if (idx < N_NODES) s += counts[idx]; }
  sd[tid] = s; __syncthreads();
  for (int off = 1; off < 1024; off <<= 1) {
    int v = (tid >= off) ? sd[tid - off] : 0;
    __syncthreads();
    sd[tid] += v;
    __syncthreads();
  }
  int run = sd[tid] - s;  // exclusive prefix
  for (int i = 0; i < CH; ++i) {
    int idx = i0 + i;
    if (idx < N_NODES) { offs[idx] = run; cursor[idx] = run; run += counts[idx]; }
  }
  if (tid == 1023) offs[N_NODES] = run;
}

__global__ void scatter_k(const int* __restrict__ ei, int* __restrict__ cursor,
                          int* __restrict__ elist) {
  for (long e = blockIdx.x * (long)blockDim.x + threadIdx.x; e < N_EDGES;
       e += (long)gridDim.x * blockDim.x) {
    int d = ei[N_EDGES + e];
    int pos = atomicAdd(&cursor[d], 1);
    elist[pos] = (int)e;
  }
}

// ---------------- attention edge/softmax kernels ----------------
// per edge: alpha[h] = q[dst]·(K[src]+e)/4 ; store exp(alpha). No max-sub needed (|alpha| small).
__global__ __launch_bounds__(256) void edge_alpha(const int* __restrict__ ei,
    const f16* __restrict__ Qn, const f16* __restrict__ Kn, const f16* __restrict__ emat,
    float* __restrict__ exo) {
  int lane = threadIdx.x & 63;
  long wid = (blockIdx.x * 256L + threadIdx.x) >> 6;
  long nw = (gridDim.x * 256L) >> 6;
  for (long e = wid; e < N_EDGES; e += nw) {
    int s = ei[e], d = ei[N_EDGES + e];
    f16x2 q2 = *(const f16x2*)(Qn + (long)d * DIM + 2 * lane);
    f16x2 k2 = *(const f16x2*)(Kn + (long)s * DIM + 2 * lane);
    f16x2 e2 = *(const f16x2*)(emat + e * DIM + 2 * lane);
    float p = (float)q2[0] * ((float)k2[0] + (float)e2[0]) +
              (float)q2[1] * ((float)k2[1] + (float)e2[1]);
    p += __shfl_xor(p, 1);
    p += __shfl_xor(p, 2);
    p += __shfl_xor(p, 4);                 // 8-lane group == one head (j=2l,2l+1)
    float ex = __expf(p * 0.25f);          // /sqrt(16)
    if ((lane & 7) == 0) exo[e * 8 + (lane >> 3)] = ex;
  }
}

// per dst node: out = sum(ex*v)/sum(ex), v = e + V[src]
__global__ __launch_bounds__(256) void attn_gather(const int* __restrict__ ei,
    const int* __restrict__ offs, const int* __restrict__ elist, const float* __restrict__ exv,
    const f16* __restrict__ emat, const f16* __restrict__ Vn, float* __restrict__ outp) {
  int n = blockIdx.x * 4 + (threadIdx.x >> 6);
  if (n >= N_NODES) return;
  int lane = threadIdx.x & 63;
  int rs = offs[n], re = offs[n + 1];
  float a0 = 0.f, a1 = 0.f, den = 0.f;
  for (int i = rs; i < re; ++i) {
    int eid = elist[i];
    int s = ei[eid];  // src
    float exh = exv[(long)eid * 8 + (lane >> 3)];
    f16x2 e2 = *(const f16x2*)(emat + (long)eid * DIM + 2 * lane);
    f16x2 v2 = *(const f16x2*)(Vn + (long)s * DIM + 2 * lane);
    a0 += exh * ((float)e2[0] + (float)v2[0]);
    a1 += exh * ((float)e2[1] + (float)v2[1]);
    den += exh;
  }
  float inv = 1.f / (den + 1e-16f);
  float2 o; o.x = a0 * inv; o.y = a1 * inv;
  *(float2*)(outp + (long)n * DIM + 2 * lane) = o;
}

// out = base + LN(xa [+ xb]) * g + b  (two-pass mean/var, exact)
__global__ __launch_bounds__(256) void post_ln(const float* __restrict__ xa,
    const float* __restrict__ xb, const float* __restrict__ base,
    const float* __restrict__ g, const float* __restrict__ b, float* __restrict__ outp) {
  int n = blockIdx.x * 4 + (threadIdx.x >> 6);
  if (n >= N_NODES) return;
  int lane = threadIdx.x & 63;
  float2 x = *(const float2*)(xa + (long)n * DIM + 2 * lane);
  if (xb) {
    float2 y = *(const float2*)(xb + (long)n * DIM + 2 * lane);
    x.x += y.x; x.y += y.y;
  }
  float sm = x.x + x.y;
  for (int m = 1; m < 64; m <<= 1) sm += __shfl_xor(sm, m);
  float mu = sm * (1.f / 128.f);
  float dx = x.x - mu, dy = x.y - mu;
  float ss = dx * dx + dy * dy;
  for (int m = 1; m < 64; m <<= 1) ss += __shfl_xor(ss, m);
  float r = rsqrtf(ss * (1.f / 128.f) + 1e-5f);
  float2 gg = *(const float2*)(g + 2 * lane);
  float2 bb = *(const float2*)(b + 2 * lane);
  float2 bs = *(const float2*)(base + (long)n * DIM + 2 * lane);
  float2 o;
  o.x = bs.x + dx * r * gg.x + bb.x;
  o.y = bs.y + dy * r * gg.y + bb.y;
  *(float2*)(outp + (long)n * DIM + 2 * lane) = o;
}

// ---------------- launch ----------------
extern "C" void kernel_launch(void* const* d_in, const int* in_sizes, int n_in,
                              void* d_out, int out_size, void* d_ws, size_t ws_size,
                              hipStream_t stream) {
  (void)in_sizes; (void)n_in; (void)out_size; (void)ws_size;
  const int*   ei  = (const int*)d_in[0];
  const float* x0  = (const float*)d_in[1];
  const float* ea  = (const float*)d_in[2];
  const float* Wq  = (const float*)d_in[3];  const float* bq = (const float*)d_in[4];
  const float* Wk  = (const float*)d_in[5];  const float* bk = (const float*)d_in[6];
  const float* Wv  = (const float*)d_in[7];  const float* bv = (const float*)d_in[8];
  const float* We  = (const float*)d_in[9];  const float* be = (const float*)d_in[10];
  const float* Wsk = (const float*)d_in[11]; const float* bsk = (const float*)d_in[12];
  const float* W1  = (const float*)d_in[13]; const float* b1 = (const float*)d_in[14];
  const float* W2  = (const float*)d_in[15]; const float* b2 = (const float*)d_in[16];
  const float* g1  = (const float*)d_in[17]; const float* lb1 = (const float*)d_in[18];
  const float* g2  = (const float*)d_in[19]; const float* lb2 = (const float*)d_in[20];

  char* ws = (char*)d_ws;
  f16*   Qn     = (f16*)(ws + 0);
  f16*   Kn     = (f16*)(ws + 12800000L);
  f16*   Vn     = (f16*)(ws + 25600000L);
  float* Skip   = (float*)(ws + 38400000L);
  float* exv    = (float*)(ws + 64000000L);
  int*   offs   = (int*)(ws + 89600000L);
  int*   cursor = (int*)(ws + 89800192L);
  int*   counts = (int*)(ws + 90000384L);
  int*   elist  = (int*)(ws + 90200576L);
  f16*   emat   = (f16*)(ws + 93400576L);
  float* node1  = (float*)(ws + 298200576L);
  float* hid    = (float*)(ws + 38400000L);  // reuse Skip (dead after post1)
  float* h2     = (float*)(ws + 0);          // reuse Qn/Kn (dead after attn)
  float* attn   = (float*)d_out;             // staging; overwritten by final post_ln

  hipMemsetAsync(counts, 0, N_NODES * sizeof(int), stream);
  hist_k<<<1024, 256, 0, stream>>>(ei, counts);
  scan_k<<<1, 1024, 0, stream>>>(counts, offs, cursor);
  scatter_k<<<1024, 256, 0, stream>>>(ei, cursor, elist);

  node_qkvs<<<(N_NODES + 127) / 128, 256, 0, stream>>>(x0, Wq, bq, Wk, bk, Wv, bv, Wsk, bsk,
                                                       Qn, Kn, Vn, Skip);
  gemm128<1, 0><<<N_EDGES / 128, 256, 0, stream>>>(ea, (long)N_EDGES, We, be, emat);
  edge_alpha<<<4096, 256, 0, stream>>>(ei, Qn, Kn, emat, exv);
  attn_gather<<<12500, 256, 0, stream>>>(ei, offs, elist, exv, emat, Vn, attn);
  post_ln<<<12500, 256, 0, stream>>>(attn, Skip, x0, g1, lb1, node1);
  gemm128<0, 1><<<(N_NODES + 127) / 128, 256, 0, stream>>>(node1, (long)N_NODES, W1, b1, hid);
  gemm128<0, 0><<<(N_NODES + 127) / 128, 256, 0, stream>>>(hid, (long)N_NODES, W2, b2, h2);
  post_ln<<<12500, 256, 0, stream>>>(h2, nullptr, node1, g2, lb2, (float*)d_out);
}